// Round 7
// baseline (1710.494 us; speedup 1.0000x reference)
//
#include <hip/hip_runtime.h>
#include <math.h>

#define NN 50000
#define NE 800000
#define DD 128
#define NBUCK 196        // ceil(NN/256) buckets of 256 nodes
#define EPB 2048         // edges per hist/partition block
#define PB 391           // ceil(NE/EPB)
#define CONVB 6250       // NN*DD/4/256
#define GRID 960         // 4 blocks/CU x 240 CUs margin; __launch_bounds__(256,4) guarantees residency
#define AGGT 3125        // 16-node agg tiles
#define GEMB 391         // 128-row gemm tiles
#define PREPV (CONVB + 320 + PB)

typedef unsigned short u16;
typedef unsigned long long u64t;
typedef short s8v __attribute__((ext_vector_type(8)));    // 8 bf16 (4 VGPRs)
typedef float f16v __attribute__((ext_vector_type(16)));  // 16 fp32 acc

__device__ __forceinline__ u16 f2bf(float f) {  // RNE fp32->bf16
    unsigned u = __float_as_uint(f);
    return (u16)((u + 0x7FFFu + ((u >> 16) & 1u)) >> 16);
}
__device__ __forceinline__ float bflo(unsigned u) { return __uint_as_float(u << 16); }
__device__ __forceinline__ float bfhi(unsigned u) { return __uint_as_float(u & 0xFFFF0000u); }

// ---- zero bcnt + claim + barrier counter (graph-capture-safe; runs every replay) ----
__global__ __launch_bounds__(256) void zero_kernel(int* __restrict__ p, int n) {
    int i = threadIdx.x + blockIdx.x * 256;
    if (i < n) p[i] = 0;
}

// ---- device-wide cumulative barrier: all GRID blocks co-resident by construction ----
// Correct: a block arrives at barrier k having contributed k-1; others stuck at k
// contribute <= k each, so ctr <= GRID*k - 1 until the last arrival => no early pass.
__device__ __forceinline__ void gbar(int* __restrict__ ctr, int target) {
    __syncthreads();
    if (threadIdx.x == 0) {
        __threadfence();  // belt: release all prior writes
        __hip_atomic_fetch_add(ctr, 1, __ATOMIC_ACQ_REL, __HIP_MEMORY_SCOPE_AGENT);
        while (__hip_atomic_load(ctr, __ATOMIC_ACQUIRE, __HIP_MEMORY_SCOPE_AGENT) < target)
            __builtin_amdgcn_s_sleep(8);
        __threadfence();  // belt: acquire
    }
    __syncthreads();
}

// pack order: out[((c*4+n)*64+l)*8+j] = Wcat[col=n*32+(l&31)][k=c*16+(l>>5)*8+j]
__device__ __forceinline__ void pack_one(const float* __restrict__ Wl,
                                         const float* __restrict__ Wr,
                                         bool two, int o, u16* __restrict__ out) {
    int j = o & 7;
    int l = (o >> 3) & 63;
    int cn = o >> 9;
    int n = cn & 3;
    int c = cn >> 2;
    int colj = n * 32 + (l & 31);
    int k = c * 16 + (l >> 5) * 8 + j;
    float v;
    if (two) v = (k < DD) ? Wl[colj * DD + k] : Wr[colj * DD + (k - DD)];
    else     v = Wl[colj * DD + k];
    out[o] = f2bf(v);
}

// ---- segmented max for one node (16 lanes/node, 16B/lane, batch-8 issue) ----
__device__ __forceinline__ void vmax8(float* m, uint4 v) {
    m[0] = fmaxf(m[0], bflo(v.x)); m[1] = fmaxf(m[1], bfhi(v.x));
    m[2] = fmaxf(m[2], bflo(v.y)); m[3] = fmaxf(m[3], bfhi(v.y));
    m[4] = fmaxf(m[4], bflo(v.z)); m[5] = fmaxf(m[5], bfhi(v.z));
    m[6] = fmaxf(m[6], bflo(v.w)); m[7] = fmaxf(m[7], bfhi(v.w));
}

__device__ __forceinline__ void agg_node(const uint4* __restrict__ xb4,
                                         const int* __restrict__ rp,
                                         const int* __restrict__ cl,
                                         uint4* __restrict__ ag4,
                                         int node, int j) {
    int s0 = rp[node], s1 = rp[node + 1];
    uint4 o = make_uint4(0u, 0u, 0u, 0u);
    if (s0 < s1) {
        float m0[8], m1[8], m2[8], m3[8];
#pragma unroll
        for (int q = 0; q < 8; q++) { m0[q] = m1[q] = m2[q] = m3[q] = -INFINITY; }
        int i = s0;
        for (; i + 8 <= s1; i += 8) {
            int c0 = cl[i],     c1 = cl[i + 1], c2 = cl[i + 2], c3 = cl[i + 3];
            int c4 = cl[i + 4], c5 = cl[i + 5], c6 = cl[i + 6], c7 = cl[i + 7];
            uint4 v0 = xb4[(size_t)c0 * 16 + j];
            uint4 v1 = xb4[(size_t)c1 * 16 + j];
            uint4 v2 = xb4[(size_t)c2 * 16 + j];
            uint4 v3 = xb4[(size_t)c3 * 16 + j];
            uint4 v4 = xb4[(size_t)c4 * 16 + j];
            uint4 v5 = xb4[(size_t)c5 * 16 + j];
            uint4 v6 = xb4[(size_t)c6 * 16 + j];
            uint4 v7 = xb4[(size_t)c7 * 16 + j];
            vmax8(m0, v0); vmax8(m1, v1); vmax8(m2, v2); vmax8(m3, v3);
            vmax8(m0, v4); vmax8(m1, v5); vmax8(m2, v6); vmax8(m3, v7);
        }
        for (; i + 4 <= s1; i += 4) {
            int c0 = cl[i], c1 = cl[i + 1], c2 = cl[i + 2], c3 = cl[i + 3];
            uint4 v0 = xb4[(size_t)c0 * 16 + j];
            uint4 v1 = xb4[(size_t)c1 * 16 + j];
            uint4 v2 = xb4[(size_t)c2 * 16 + j];
            uint4 v3 = xb4[(size_t)c3 * 16 + j];
            vmax8(m0, v0); vmax8(m1, v1); vmax8(m2, v2); vmax8(m3, v3);
        }
        for (; i < s1; i++) vmax8(m0, xb4[(size_t)cl[i] * 16 + j]);
#pragma unroll
        for (int q = 0; q < 8; q++) m0[q] = fmaxf(fmaxf(m0[q], m1[q]), fmaxf(m2[q], m3[q]));
        o.x = (__float_as_uint(m0[0]) >> 16) | (__float_as_uint(m0[1]) & 0xFFFF0000u);
        o.y = (__float_as_uint(m0[2]) >> 16) | (__float_as_uint(m0[3]) & 0xFFFF0000u);
        o.z = (__float_as_uint(m0[4]) >> 16) | (__float_as_uint(m0[5]) & 0xFFFF0000u);
        o.w = (__float_as_uint(m0[6]) >> 16) | (__float_as_uint(m0[7]) & 0xFFFF0000u);
    }
    ag4[(size_t)node * 16 + j] = o;
}

// ---- 128x128 GEMM tile, A=[srcA|srcB] K=256, relu'd bf16 -> LDS tile ----
// (acc stays in regs; caller decides epilogue). C/D: col=lane&31, row=(r&3)+8*(r>>2)+4*(lane>>5)
__device__ __forceinline__ void gemm_tile_to_lds(char* __restrict__ Ab,
                                                 const u16* __restrict__ srcA,
                                                 const u16* __restrict__ srcB,
                                                 const u16* __restrict__ Bpk,
                                                 const float* __restrict__ bias,
                                                 int row0, int tid) {
    int wt = tid >> 6;
    int lane = tid & 63;
    int rload = row0 + wt * 32 + (lane & 31);
    if (rload > NN - 1) rload = NN - 1;
    int koff = (lane >> 5) * 8;
    const s8v* Bv = (const s8v*)Bpk;
    f16v acc[4];
#pragma unroll
    for (int n = 0; n < 4; n++) acc[n] = (f16v)(0.0f);
#pragma unroll
    for (int c = 0; c < 16; c++) {
        const u16* s = srcA;
        int kk = c * 16;
        if (c >= 8) { s = srcB; kk = (c - 8) * 16; }
        s8v a = *(const s8v*)(s + (size_t)rload * DD + kk + koff);
#pragma unroll
        for (int n = 0; n < 4; n++) {
            s8v b = Bv[(c * 4 + n) * 64 + lane];
            acc[n] = __builtin_amdgcn_mfma_f32_32x32x16_bf16(a, b, acc[n], 0, 0, 0);
        }
    }
    int rowadd = 4 * (lane >> 5);
#pragma unroll
    for (int n = 0; n < 4; n++) {
        int colj = n * 32 + (lane & 31);
        float bj = bias[colj];
#pragma unroll
        for (int r = 0; r < 16; r++) {
            int rloc = wt * 32 + (r & 3) + 8 * (r >> 2) + rowadd;
            float v = fmaxf(acc[n][r] + bj, 0.0f);
            *(u16*)(Ab + rloc * 256 + ((colj * 2) ^ ((rloc & 7) << 4))) = f2bf(v);
        }
    }
}

// =============================== THE MEGA KERNEL ===============================
// prep | bar | partition | bar | csr | bar | agg0 | bar | gemm0 | bar | agg1 | bar | gemmF
__global__ __launch_bounds__(256, 4) void mega(
        const float4* __restrict__ x4,
        const int* __restrict__ ei,
        const float* __restrict__ Wl, const float* __restrict__ Wr,
        const float* __restrict__ W,
        const float* __restrict__ bl, const float* __restrict__ bfin,
        u16* __restrict__ hb0, u16* __restrict__ hb1,
        u16* __restrict__ aggb,
        u16* __restrict__ Bpk0, u16* __restrict__ Bpk1, u16* __restrict__ Bpkf,
        unsigned* __restrict__ packed,
        int* __restrict__ rowptr, int* __restrict__ col,
        int* __restrict__ bcnt, int* __restrict__ claim,
        int* __restrict__ ctr,
        float* __restrict__ out) {
    __shared__ __align__(16) char smem[32768];
    int bid = blockIdx.x;
    int tid = threadIdx.x;

    // ---------------- P0: prep (conv | packs | hist) ----------------
    for (int vb = bid; vb < PREPV; vb += GRID) {
        if (vb < CONVB) {
            int i = vb * 256 + tid;
            float4 v = x4[i];
            ushort4 o;
            o.x = f2bf(v.x); o.y = f2bf(v.y); o.z = f2bf(v.z); o.w = f2bf(v.w);
            ((ushort4*)hb0)[i] = o;
        } else if (vb < CONVB + 128) {
            pack_one(Wl, Wr, true, (vb - CONVB) * 256 + tid, Bpk0);
        } else if (vb < CONVB + 256) {
            pack_one(Wl + DD * DD, Wr + DD * DD, true, (vb - CONVB - 128) * 256 + tid, Bpk1);
        } else if (vb < CONVB + 320) {
            pack_one(W, W, false, (vb - CONVB - 256) * 256 + tid, Bpkf);
        } else {
            int* h = (int*)smem;
            for (int i = tid; i < NBUCK; i += 256) h[i] = 0;
            __syncthreads();
            int e0 = (vb - (CONVB + 320)) * EPB;
#pragma unroll
            for (int i = 0; i < 8; i++) {
                int e = e0 + i * 256 + tid;
                if (e < NE) atomicAdd(&h[ei[NE + e] >> 8], 1);
            }
            __syncthreads();
            for (int i = tid; i < NBUCK; i += 256)
                if (h[i]) atomicAdd(&bcnt[i], h[i]);
            __syncthreads();  // protect smem before next vb iteration
        }
    }
    gbar(ctr, 1 * GRID);

    // ---------------- P1: partition ----------------
    if (bid < PB) {
        int* sc   = (int*)smem;        // 256
        int* bb   = sc + 256;          // 196 (padded 256)
        int* h    = bb + 256;          // 196
        int* base = h + 256;           // 196
        int t = tid;
        int v = (t < NBUCK) ? bcnt[t] : 0;
        sc[t] = v;
        __syncthreads();
        for (int o = 1; o < 256; o <<= 1) {
            int u = (t >= o) ? sc[t - o] : 0;
            __syncthreads();
            sc[t] += u;
            __syncthreads();
        }
        if (t < NBUCK) bb[t] = sc[t] - v;
        if (t == 0 && bid == 0) rowptr[NN] = NE;
        for (int i = t; i < NBUCK; i += 256) h[i] = 0;
        __syncthreads();
        int e0 = bid * EPB;
        int dsts[8], srcs[8];
#pragma unroll
        for (int i = 0; i < 8; i++) {
            int e = e0 + i * 256 + t;
            if (e < NE) {
                dsts[i] = ei[NE + e];
                srcs[i] = ei[e];
                atomicAdd(&h[dsts[i] >> 8], 1);
            } else dsts[i] = -1;
        }
        __syncthreads();
        for (int i = t; i < NBUCK; i += 256) {
            int c = h[i];
            base[i] = c ? bb[i] + atomicAdd(&claim[i], c) : 0;
        }
        __syncthreads();
        for (int i = t; i < NBUCK; i += 256) h[i] = 0;  // local cursor
        __syncthreads();
#pragma unroll
        for (int i = 0; i < 8; i++) {
            if (dsts[i] >= 0) {
                int bk = dsts[i] >> 8;
                int r = atomicAdd(&h[bk], 1);
                packed[base[bk] + r] = (unsigned)srcs[i] | ((unsigned)(dsts[i] & 255) << 16);
            }
        }
    }
    gbar(ctr, 2 * GRID);

    // ---------------- P2: per-bucket counting sort -> rowptr + col ----------------
    if (bid < NBUCK) {
        int* sc  = (int*)smem;   // 256
        int* deg = sc + 256;     // 256
        int* off = deg + 256;    // 256
        int t = tid;
        int v0 = (t < NBUCK) ? bcnt[t] : 0;
        sc[t] = v0;
        __syncthreads();
        for (int o = 1; o < 256; o <<= 1) {
            int u = (t >= o) ? sc[t - o] : 0;
            __syncthreads();
            sc[t] += u;
            __syncthreads();
        }
        int bk = bid;
        int cnt = bcnt[bk];
        int base = sc[bk] - cnt;
        deg[t] = 0;
        __syncthreads();
        for (int i = t; i < cnt; i += 256) atomicAdd(&deg[packed[base + i] >> 16], 1);
        __syncthreads();
        int v = deg[t];
        off[t] = v;
        __syncthreads();
        for (int o = 1; o < 256; o <<= 1) {
            int u = (t >= o) ? off[t - o] : 0;
            __syncthreads();
            off[t] += u;
            __syncthreads();
        }
        int ex = off[t] - v;
        int node = (bk << 8) + t;
        if (node < NN) rowptr[node] = base + ex;
        deg[t] = ex;
        __syncthreads();
        for (int i = t; i < cnt; i += 256) {
            unsigned p = packed[base + i];
            int dl = p >> 16;
            int r = atomicAdd(&deg[dl], 1);
            col[base + r] = (int)(p & 0xFFFFu);
        }
    }
    gbar(ctr, 3 * GRID);

    // ---------------- P3: agg layer 0 (hb0 -> aggb) ----------------
    {
        int j = tid & 15, nl = tid >> 4;
        for (int vb = bid; vb < AGGT; vb += GRID) {
            int node = vb * 16 + nl;
            if (node < NN)
                agg_node((const uint4*)hb0, rowptr, col, (uint4*)aggb, node, j);
        }
    }
    gbar(ctr, 4 * GRID);

    // ---------------- P4: gemm0 ([aggb|hb0] -> relu bf16 hb1) ----------------
    if (bid < GEMB) {
        int row0 = bid * 128;
        gemm_tile_to_lds(smem, aggb, hb0, Bpk0, bl, row0, tid);
        __syncthreads();
#pragma unroll
        for (int it = 0; it < 16; it++) {
            int flat = it * 256 + tid;
            int rl = flat >> 5;
            int p  = flat & 31;
            u64t v = *(const u64t*)(smem + rl * 256 + ((p * 8) ^ ((rl & 7) << 4)));
            int row = row0 + rl;
            if (row < NN)
                *(u64t*)(hb1 + (size_t)row * DD + p * 4) = v;
        }
    }
    gbar(ctr, 5 * GRID);

    // ---------------- P5: agg layer 1 (hb1 -> aggb) ----------------
    {
        int j = tid & 15, nl = tid >> 4;
        for (int vb = bid; vb < AGGT; vb += GRID) {
            int node = vb * 16 + nl;
            if (node < NN)
                agg_node((const uint4*)hb1, rowptr, col, (uint4*)aggb, node, j);
        }
    }
    gbar(ctr, 6 * GRID);

    // ---------------- P6: gemm1 + final linear (fused via LDS tile) ----------------
    if (bid < GEMB) {
        int row0 = bid * 128;
        gemm_tile_to_lds(smem, aggb, hb1, Bpk1, bl + DD, row0, tid);
        __syncthreads();
        // final GEMM: K=128 from LDS tile, B = Bpkf, fp32 out
        int wt = tid >> 6;
        int lane = tid & 63;
        int arl = wt * 32 + (lane & 31);
        int koff = (lane >> 5) * 8;
        int swz = (arl & 7) << 4;
        const s8v* Bvf = (const s8v*)Bpkf;
        f16v acc2[4];
#pragma unroll
        for (int n = 0; n < 4; n++) acc2[n] = (f16v)(0.0f);
#pragma unroll
        for (int c = 0; c < 8; c++) {
            s8v a = *(const s8v*)(smem + arl * 256 + (((c * 16 + koff) * 2) ^ swz));
#pragma unroll
            for (int n = 0; n < 4; n++) {
                s8v b = Bvf[(c * 4 + n) * 64 + lane];
                acc2[n] = __builtin_amdgcn_mfma_f32_32x32x16_bf16(a, b, acc2[n], 0, 0, 0);
            }
        }
        int rowadd = 4 * (lane >> 5);
#pragma unroll
        for (int n = 0; n < 4; n++) {
            int colj = n * 32 + (lane & 31);
            float bj = bfin[colj];
#pragma unroll
            for (int r = 0; r < 16; r++) {
                int row = row0 + wt * 32 + (r & 3) + 8 * (r >> 2) + rowadd;
                if (row < NN)
                    out[(size_t)row * DD + colj] = acc2[n][r] + bj;
            }
        }
    }
}

extern "C" void kernel_launch(void* const* d_in, const int* in_sizes, int n_in,
                              void* d_out, int out_size, void* d_ws, size_t ws_size,
                              hipStream_t stream) {
    const float* x  = (const float*)d_in[0];
    const int*   ei = (const int*)d_in[1];
    const float* Wl = (const float*)d_in[2];
    const float* bl = (const float*)d_in[3];
    const float* Wr = (const float*)d_in[4];
    const float* W  = (const float*)d_in[5];
    const float* b  = (const float*)d_in[6];
    float* out = (float*)d_out;

    // ws layout (16B-aligned chunks)
    u16* aggb = (u16*)d_ws;                         // NN*DD bf16
    u16* hb0  = aggb + (size_t)NN * DD;             // NN*DD
    u16* hb1  = hb0 + (size_t)NN * DD;              // NN*DD
    u16* Bpk0 = hb1 + (size_t)NN * DD;              // 32768
    u16* Bpk1 = Bpk0 + 32768;                       // 32768
    u16* Bpkf = Bpk1 + 32768;                       // 16384
    unsigned* packed = (unsigned*)(Bpkf + 16384);   // NE u32
    int* col    = (int*)(packed + NE);              // NE
    int* rowptr = col + NE;                         // NN+1
    int* bcnt   = rowptr + NN + 1;                  // NBUCK
    int* claim  = bcnt + NBUCK;                     // NBUCK
    int* ctr    = claim + NBUCK;                    // 1 (barrier counter)

    dim3 blk(256);
    // zero bcnt + claim + ctr (contiguous: 2*NBUCK+1 ints), then the mega kernel
    zero_kernel<<<2, blk, 0, stream>>>(bcnt, 2 * NBUCK + 1);
    mega<<<GRID, blk, 0, stream>>>(
        (const float4*)x, ei, Wl, Wr, W, bl, b,
        hb0, hb1, aggb, Bpk0, Bpk1, Bpkf,
        packed, rowptr, col, bcnt, claim, ctr, out);
}

// Round 8
// 269.801 us; speedup vs baseline: 6.3398x; 6.3398x over previous
//
#include <hip/hip_runtime.h>
#include <math.h>

#define NN 50000
#define NE 800000
#define DD 128
#define NBUCK 196        // ceil(NN/256) buckets of 256 nodes
#define EPB 2048         // edges per hist/partition block
#define PB 391           // ceil(NE/EPB)
#define CONVB 6250       // NN*DD/4/256
#define CHKS ((size_t)NN * 32)   // u16 elements per feature chunk [N][32]
#define AGGB 782         // ceil(NN/64) blocks per chunk dispatch

typedef unsigned short u16;
typedef unsigned long long u64t;
typedef short s8v __attribute__((ext_vector_type(8)));    // 8 bf16 (4 VGPRs)
typedef float f16v __attribute__((ext_vector_type(16)));  // 16 fp32 acc

__device__ __forceinline__ u16 f2bf(float f) {  // RNE fp32->bf16
    unsigned u = __float_as_uint(f);
    return (u16)((u + 0x7FFFu + ((u >> 16) & 1u)) >> 16);
}
__device__ __forceinline__ float bflo(unsigned u) { return __uint_as_float(u << 16); }
__device__ __forceinline__ float bfhi(unsigned u) { return __uint_as_float(u & 0xFFFF0000u); }

// ---- zero bcnt + claim (graph-capture-safe) ----
__global__ __launch_bounds__(256) void zero_kernel(int* __restrict__ p, int n) {
    int i = threadIdx.x + blockIdx.x * 256;
    if (i < n) p[i] = 0;
}

// ---- fused prep: x->bf16 chunk-major conv | 3x weight pack | edge histogram ----
// pack order: out[((c*4+n)*64+l)*8+j] = Wcat[col=n*32+(l&31)][k=c*16+(l>>5)*8+j]
__device__ __forceinline__ void pack_one(const float* __restrict__ Wl,
                                         const float* __restrict__ Wr,
                                         bool two, int o, u16* __restrict__ out) {
    int j = o & 7;
    int l = (o >> 3) & 63;
    int cn = o >> 9;
    int n = cn & 3;
    int c = cn >> 2;
    int colj = n * 32 + (l & 31);
    int k = c * 16 + (l >> 5) * 8 + j;
    float v;
    if (two) v = (k < DD) ? Wl[colj * DD + k] : Wr[colj * DD + (k - DD)];
    else     v = Wl[colj * DD + k];
    out[o] = f2bf(v);
}

__global__ __launch_bounds__(256) void prep_kernel(
        const float4* __restrict__ x4, u16* __restrict__ hT0,
        const float* __restrict__ Wl, const float* __restrict__ Wr,
        const float* __restrict__ W,
        u16* __restrict__ Bpk0, u16* __restrict__ Bpk1, u16* __restrict__ Bpkf,
        const int* __restrict__ ei, int* __restrict__ bcnt) {
    int bid = blockIdx.x;
    int tid = threadIdx.x;
    if (bid < CONVB) {
        int i = bid * 256 + tid;          // float4 index over [N][32]
        float4 v = x4[i];
        u64t pk = (u64t)f2bf(v.x) | ((u64t)f2bf(v.y) << 16) |
                  ((u64t)f2bf(v.z) << 32) | ((u64t)f2bf(v.w) << 48);
        int row = i >> 5, pos = i & 31;   // pos: which float4 within row
        // chunk-major: [chunk=pos>>3][row][32], 8B slot (pos&7)*4
        *(u64t*)(hT0 + ((size_t)(pos >> 3) * NN + row) * 32 + (pos & 7) * 4) = pk;
    } else if (bid < CONVB + 128) {
        pack_one(Wl, Wr, true, (bid - CONVB) * 256 + tid, Bpk0);
    } else if (bid < CONVB + 256) {
        pack_one(Wl + DD * DD, Wr + DD * DD, true, (bid - CONVB - 128) * 256 + tid, Bpk1);
    } else if (bid < CONVB + 320) {
        pack_one(W, W, false, (bid - CONVB - 256) * 256 + tid, Bpkf);
    } else {
        // coarse bucket histogram (bcnt zeroed by zero_kernel)
        __shared__ int h[NBUCK];
        for (int i = tid; i < NBUCK; i += 256) h[i] = 0;
        __syncthreads();
        int e0 = (bid - (CONVB + 320)) * EPB;
#pragma unroll
        for (int i = 0; i < 8; i++) {
            int e = e0 + i * 256 + tid;
            if (e < NE) atomicAdd(&h[ei[NE + e] >> 8], 1);
        }
        __syncthreads();
        for (int i = tid; i < NBUCK; i += 256)
            if (h[i]) atomicAdd(&bcnt[i], h[i]);
    }
}

// ---- partition edges into bucket-contiguous packed array ----
__global__ __launch_bounds__(256) void bucket_partition(const int* __restrict__ ei,
                                                        const int* __restrict__ bcnt,
                                                        int* __restrict__ claim,
                                                        unsigned* __restrict__ packed,
                                                        int* __restrict__ rowptr) {
    __shared__ int sc[256];
    __shared__ int bb[NBUCK];
    __shared__ int h[NBUCK];
    __shared__ int base[NBUCK];
    int t = threadIdx.x;
    int v = (t < NBUCK) ? bcnt[t] : 0;
    sc[t] = v;
    __syncthreads();
    for (int o = 1; o < 256; o <<= 1) {
        int u = (t >= o) ? sc[t - o] : 0;
        __syncthreads();
        sc[t] += u;
        __syncthreads();
    }
    if (t < NBUCK) bb[t] = sc[t] - v;
    if (t == 0 && blockIdx.x == 0) rowptr[NN] = NE;
    for (int i = t; i < NBUCK; i += 256) h[i] = 0;
    __syncthreads();
    int e0 = blockIdx.x * EPB;
    int dsts[8], srcs[8];
#pragma unroll
    for (int i = 0; i < 8; i++) {
        int e = e0 + i * 256 + t;
        if (e < NE) {
            dsts[i] = ei[NE + e];
            srcs[i] = ei[e];
            atomicAdd(&h[dsts[i] >> 8], 1);
        } else dsts[i] = -1;
    }
    __syncthreads();
    for (int i = t; i < NBUCK; i += 256) {
        int c = h[i];
        base[i] = c ? bb[i] + atomicAdd(&claim[i], c) : 0;
    }
    __syncthreads();
    for (int i = t; i < NBUCK; i += 256) h[i] = 0;  // reuse as local cursor
    __syncthreads();
#pragma unroll
    for (int i = 0; i < 8; i++) {
        if (dsts[i] >= 0) {
            int bk = dsts[i] >> 8;
            int r = atomicAdd(&h[bk], 1);
            packed[base[bk] + r] = (unsigned)srcs[i] | ((unsigned)(dsts[i] & 255) << 16);
        }
    }
}

// ---- per-bucket counting sort -> rowptr + col ----
__global__ __launch_bounds__(256) void bucket_csr(const unsigned* __restrict__ packed,
                                                  const int* __restrict__ bcnt,
                                                  int* __restrict__ rowptr,
                                                  int* __restrict__ col) {
    __shared__ int sc[256];
    __shared__ int deg[256];
    __shared__ int off[256];
    int t = threadIdx.x;
    int v0 = (t < NBUCK) ? bcnt[t] : 0;
    sc[t] = v0;
    __syncthreads();
    for (int o = 1; o < 256; o <<= 1) {
        int u = (t >= o) ? sc[t - o] : 0;
        __syncthreads();
        sc[t] += u;
        __syncthreads();
    }
    int bk = blockIdx.x;
    int cnt = bcnt[bk];
    int base = sc[bk] - cnt;  // exclusive scan value for this bucket
    deg[t] = 0;
    __syncthreads();
    for (int i = t; i < cnt; i += 256) atomicAdd(&deg[packed[base + i] >> 16], 1);
    __syncthreads();
    int v = deg[t];
    off[t] = v;
    __syncthreads();
    for (int o = 1; o < 256; o <<= 1) {
        int u = (t >= o) ? off[t - o] : 0;
        __syncthreads();
        off[t] += u;
        __syncthreads();
    }
    int ex = off[t] - v;
    int node = (bk << 8) + t;
    if (node < NN) rowptr[node] = base + ex;
    deg[t] = ex;  // reuse as cursor
    __syncthreads();
    for (int i = t; i < cnt; i += 256) {
        unsigned p = packed[base + i];
        int dl = p >> 16;
        int r = atomicAdd(&deg[dl], 1);
        col[base + r] = (int)(p & 0xFFFFu);
    }
}

// ---- per-chunk segmented max: ONE 32-feature chunk per DISPATCH ----
// Stream ordering serializes chunks; per-dispatch working set = NN*64B = 3.2MB
// < 4MB, so each XCD's L2 caches the whole chunk (replicated) regardless of
// block->XCD mapping. 4 lanes/node x 16B = one full 64B row per edge gather.
// No syncthreads, no queue (r5 lessons); independent 4-lane groups.
__device__ __forceinline__ void vmax8(float* m, uint4 v) {
    m[0] = fmaxf(m[0], bflo(v.x)); m[1] = fmaxf(m[1], bfhi(v.x));
    m[2] = fmaxf(m[2], bflo(v.y)); m[3] = fmaxf(m[3], bfhi(v.y));
    m[4] = fmaxf(m[4], bflo(v.z)); m[5] = fmaxf(m[5], bfhi(v.z));
    m[6] = fmaxf(m[6], bflo(v.w)); m[7] = fmaxf(m[7], bfhi(v.w));
}

__global__ __launch_bounds__(256) void agg_chunk(const uint4* __restrict__ src4,
                                                 const int* __restrict__ rowptr,
                                                 const int* __restrict__ col,
                                                 uint4* __restrict__ dst4) {
    int node = blockIdx.x * 64 + (threadIdx.x >> 2);
    if (node >= NN) return;
    int q = threadIdx.x & 3;
    int s0 = rowptr[node], s1 = rowptr[node + 1];
    uint4 o = make_uint4(0u, 0u, 0u, 0u);
    if (s0 < s1) {
        float m0[8], m1[8];
#pragma unroll
        for (int k = 0; k < 8; k++) { m0[k] = m1[k] = -INFINITY; }
        int i = s0;
        for (; i + 8 <= s1; i += 8) {
            int c0 = col[i],     c1 = col[i + 1], c2 = col[i + 2], c3 = col[i + 3];
            int c4 = col[i + 4], c5 = col[i + 5], c6 = col[i + 6], c7 = col[i + 7];
            uint4 v0 = src4[(size_t)c0 * 4 + q];
            uint4 v1 = src4[(size_t)c1 * 4 + q];
            uint4 v2 = src4[(size_t)c2 * 4 + q];
            uint4 v3 = src4[(size_t)c3 * 4 + q];
            uint4 v4 = src4[(size_t)c4 * 4 + q];
            uint4 v5 = src4[(size_t)c5 * 4 + q];
            uint4 v6 = src4[(size_t)c6 * 4 + q];
            uint4 v7 = src4[(size_t)c7 * 4 + q];
            vmax8(m0, v0); vmax8(m1, v1); vmax8(m0, v2); vmax8(m1, v3);
            vmax8(m0, v4); vmax8(m1, v5); vmax8(m0, v6); vmax8(m1, v7);
        }
        for (; i + 2 <= s1; i += 2) {
            uint4 v0 = src4[(size_t)col[i] * 4 + q];
            uint4 v1 = src4[(size_t)col[i + 1] * 4 + q];
            vmax8(m0, v0); vmax8(m1, v1);
        }
        if (i < s1) vmax8(m0, src4[(size_t)col[i] * 4 + q]);
#pragma unroll
        for (int k = 0; k < 8; k++) m0[k] = fmaxf(m0[k], m1[k]);
        // values exact bf16 -> pack by truncation
        o.x = (__float_as_uint(m0[0]) >> 16) | (__float_as_uint(m0[1]) & 0xFFFF0000u);
        o.y = (__float_as_uint(m0[2]) >> 16) | (__float_as_uint(m0[3]) & 0xFFFF0000u);
        o.z = (__float_as_uint(m0[4]) >> 16) | (__float_as_uint(m0[5]) & 0xFFFF0000u);
        o.w = (__float_as_uint(m0[6]) >> 16) | (__float_as_uint(m0[7]) & 0xFFFF0000u);
    }
    dst4[(size_t)node * 4 + q] = o;
}

// ---- chunk-major A-fragment address: k -> [k>>5][row][k&31] ----
__device__ __forceinline__ const s8v* afrag(const u16* __restrict__ cm, int row, int k) {
    return (const s8v*)(cm + ((size_t)(k >> 5) * NN + row) * 32 + (k & 31));
}

// ---------------- MFMA GEMM layer 0: chunk-major in, chunk-major out ----------------
// out[row][col] = relu(bias[col] + sum_k A[row][k]*Wcat[col][k]); A=[aggT|hT0], K=256.
__global__ __launch_bounds__(256) void mfma_gemm0(const u16* __restrict__ aggT,
                                                  const u16* __restrict__ hT0,
                                                  const u16* __restrict__ Bpk,
                                                  const float* __restrict__ bias,
                                                  u16* __restrict__ hT1) {
    __shared__ u16 As[128 * 128];  // 32 KB, XOR-swizzled rows
    char* Ab = (char*)As;
    int tid = threadIdx.x;
    int wt = tid >> 6;
    int lane = tid & 63;
    int row0 = blockIdx.x * 128;
    int rload = row0 + wt * 32 + (lane & 31);
    if (rload > NN - 1) rload = NN - 1;  // clamp OOB loads
    int koff = (lane >> 5) * 8;
    const s8v* Bv = (const s8v*)Bpk;

    f16v acc[4];
#pragma unroll
    for (int n = 0; n < 4; n++) acc[n] = (f16v)(0.0f);

#pragma unroll
    for (int c = 0; c < 16; c++) {
        s8v a = (c < 8) ? *afrag(aggT, rload, c * 16 + koff)
                        : *afrag(hT0, rload, (c - 8) * 16 + koff);
#pragma unroll
        for (int n = 0; n < 4; n++) {
            s8v b = Bv[(c * 4 + n) * 64 + lane];
            acc[n] = __builtin_amdgcn_mfma_f32_32x32x16_bf16(a, b, acc[n], 0, 0, 0);
        }
    }

    // relu'd bf16 acc -> LDS (C/D layout col=lane&31, row=(reg&3)+8*(reg>>2)+4*(lane>>5))
    int rowadd = 4 * (lane >> 5);
#pragma unroll
    for (int n = 0; n < 4; n++) {
        int colj = n * 32 + (lane & 31);
        float bj = bias[colj];
#pragma unroll
        for (int r = 0; r < 16; r++) {
            int rloc = wt * 32 + (r & 3) + 8 * (r >> 2) + rowadd;
            float v = fmaxf(acc[n][r] + bj, 0.0f);
            *(u16*)(Ab + rloc * 256 + ((colj * 2) ^ ((rloc & 7) << 4))) = f2bf(v);
        }
    }
    __syncthreads();

    // coalesced chunk-major store from LDS (8B per thread per iter)
#pragma unroll
    for (int it = 0; it < 16; it++) {
        int flat = it * 256 + tid;   // 0..4095
        int rl = flat >> 5;          // 0..127
        int p  = flat & 31;          // 8B group within row (4 bf16)
        u64t v = *(const u64t*)(Ab + rl * 256 + ((p * 8) ^ ((rl & 7) << 4)));
        int row = row0 + rl;
        if (row < NN)
            *(u64t*)(hT1 + ((size_t)(p >> 3) * NN + row) * 32 + (p & 7) * 4) = v;
    }
}

// ---- layer-1 GEMM + final linear fused: relu bf16 tile -> LDS -> 2nd MFMA ----
__global__ __launch_bounds__(256) void gemm_final(const u16* __restrict__ aggT,
                                                  const u16* __restrict__ hT1,
                                                  const u16* __restrict__ Bpk,
                                                  const float* __restrict__ bias,
                                                  const u16* __restrict__ Bpkf,
                                                  const float* __restrict__ bfin,
                                                  float* __restrict__ out) {
    __shared__ u16 As[128 * 128];  // 32 KB, XOR-swizzled rows
    char* Ab = (char*)As;
    int tid = threadIdx.x;
    int wt = tid >> 6;
    int lane = tid & 63;
    int row0 = blockIdx.x * 128;
    int arl = wt * 32 + (lane & 31);
    int rg = row0 + arl;
    if (rg > NN - 1) rg = NN - 1;
    int koff = (lane >> 5) * 8;
    int swz = (arl & 7) << 4;
    const s8v* Bv = (const s8v*)Bpk;

    f16v acc[4];
#pragma unroll
    for (int n = 0; n < 4; n++) acc[n] = (f16v)(0.0f);

#pragma unroll
    for (int c = 0; c < 16; c++) {
        s8v a = (c < 8) ? *afrag(aggT, rg, c * 16 + koff)
                        : *afrag(hT1, rg, (c - 8) * 16 + koff);
#pragma unroll
        for (int n = 0; n < 4; n++) {
            s8v b = Bv[(c * 4 + n) * 64 + lane];
            acc[n] = __builtin_amdgcn_mfma_f32_32x32x16_bf16(a, b, acc[n], 0, 0, 0);
        }
    }

    // relu'd bf16 acc -> LDS (this tile IS the A-operand of the final linear)
    int rowadd = 4 * (lane >> 5);
#pragma unroll
    for (int n = 0; n < 4; n++) {
        int colj = n * 32 + (lane & 31);
        float bj = bias[colj];
#pragma unroll
        for (int r = 0; r < 16; r++) {
            int rloc = wt * 32 + (r & 3) + 8 * (r >> 2) + rowadd;
            float v = fmaxf(acc[n][r] + bj, 0.0f);
            *(u16*)(Ab + rloc * 256 + ((colj * 2) ^ ((rloc & 7) << 4))) = f2bf(v);
        }
    }
    __syncthreads();

    // final GEMM: K=128 from LDS, B = Bpkf
    const s8v* Bvf = (const s8v*)Bpkf;
    f16v acc2[4];
#pragma unroll
    for (int n = 0; n < 4; n++) acc2[n] = (f16v)(0.0f);
#pragma unroll
    for (int c = 0; c < 8; c++) {
        s8v a = *(const s8v*)(Ab + arl * 256 + (((c * 16 + koff) * 2) ^ swz));
#pragma unroll
        for (int n = 0; n < 4; n++) {
            s8v b = Bvf[(c * 4 + n) * 64 + lane];
            acc2[n] = __builtin_amdgcn_mfma_f32_32x32x16_bf16(a, b, acc2[n], 0, 0, 0);
        }
    }
#pragma unroll
    for (int n = 0; n < 4; n++) {
        int colj = n * 32 + (lane & 31);
        float bj = bfin[colj];
#pragma unroll
        for (int r = 0; r < 16; r++) {
            int row = row0 + wt * 32 + (r & 3) + 8 * (r >> 2) + rowadd;
            if (row < NN)
                out[(size_t)row * DD + colj] = acc2[n][r] + bj;
        }
    }
}

extern "C" void kernel_launch(void* const* d_in, const int* in_sizes, int n_in,
                              void* d_out, int out_size, void* d_ws, size_t ws_size,
                              hipStream_t stream) {
    const float* x  = (const float*)d_in[0];
    const int*   ei = (const int*)d_in[1];
    const float* Wl = (const float*)d_in[2];
    const float* bl = (const float*)d_in[3];
    const float* Wr = (const float*)d_in[4];
    const float* W  = (const float*)d_in[5];
    const float* b  = (const float*)d_in[6];
    float* out = (float*)d_out;

    // ws layout (16B-aligned chunks); all feature buffers CHUNK-MAJOR [4][N][32]
    u16* aggT = (u16*)d_ws;                         // NN*DD bf16
    u16* hT0  = aggT + (size_t)NN * DD;             // NN*DD
    u16* hT1  = hT0 + (size_t)NN * DD;              // NN*DD
    u16* Bpk0 = hT1 + (size_t)NN * DD;              // 32768
    u16* Bpk1 = Bpk0 + 32768;                       // 32768
    u16* Bpkf = Bpk1 + 32768;                       // 16384
    unsigned* packed = (unsigned*)(Bpkf + 16384);   // NE u32
    int* col    = (int*)(packed + NE);              // NE
    int* rowptr = col + NE;                         // NN+1
    int* bcnt   = rowptr + NN + 1;                  // NBUCK
    int* claim  = bcnt + NBUCK;                     // NBUCK

    dim3 blk(256);
    int gemmBlocks = (NN + 127) / 128;   // 391
    int prepBlocks = CONVB + 320 + PB;   // conv + 3 packs + hist

    // zero bcnt+claim, then fused prep (conv->chunk-major | packs | hist)
    zero_kernel<<<2, blk, 0, stream>>>(bcnt, 2 * NBUCK);
    prep_kernel<<<prepBlocks, blk, 0, stream>>>(
        (const float4*)x, hT0, Wl, Wr, W, Bpk0, Bpk1, Bpkf, ei, bcnt);

    // CSR build
    bucket_partition<<<PB, blk, 0, stream>>>(ei, bcnt, claim, packed, rowptr);
    bucket_csr<<<NBUCK, blk, 0, stream>>>(packed, bcnt, rowptr, col);

    // Layer 0: 4 chunk-serialized agg dispatches (3.2MB working set each), then GEMM
    for (int c = 0; c < 4; c++)
        agg_chunk<<<AGGB, blk, 0, stream>>>(
            (const uint4*)(hT0 + c * CHKS), rowptr, col, (uint4*)(aggT + c * CHKS));
    mfma_gemm0<<<gemmBlocks, blk, 0, stream>>>(aggT, hT0, Bpk0, bl, hT1);

    // Layer 1: 4 chunk aggs + fused GEMM+final linear
    for (int c = 0; c < 4; c++)
        agg_chunk<<<AGGB, blk, 0, stream>>>(
            (const uint4*)(hT1 + c * CHKS), rowptr, col, (uint4*)(aggT + c * CHKS));
    gemm_final<<<gemmBlocks, blk, 0, stream>>>(aggT, hT1, Bpk1, bl + DD, Bpkf, b, out);
}

// Round 9
// 237.653 us; speedup vs baseline: 7.1974x; 1.1353x over previous
//
#include <hip/hip_runtime.h>
#include <math.h>

#define NN 50000
#define NE 800000
#define DD 128
#define NBUCK 196        // ceil(NN/256) buckets of 256 nodes
#define EPB 2048         // edges per hist/partition block
#define PB 391           // ceil(NE/EPB)
#define CONVB 6250       // NN*DD/4/256

typedef unsigned short u16;
typedef unsigned long long u64t;
typedef short s8v __attribute__((ext_vector_type(8)));    // 8 bf16 (4 VGPRs)
typedef float f16v __attribute__((ext_vector_type(16)));  // 16 fp32 acc

__device__ __forceinline__ u16 f2bf(float f) {  // RNE fp32->bf16
    unsigned u = __float_as_uint(f);
    return (u16)((u + 0x7FFFu + ((u >> 16) & 1u)) >> 16);
}
__device__ __forceinline__ float bflo(unsigned u) { return __uint_as_float(u << 16); }
__device__ __forceinline__ float bfhi(unsigned u) { return __uint_as_float(u & 0xFFFF0000u); }

// ---- zero bcnt + claim (graph-capture-safe) ----
__global__ __launch_bounds__(256) void zero_kernel(int* __restrict__ p, int n) {
    int i = threadIdx.x + blockIdx.x * 256;
    if (i < n) p[i] = 0;
}

// ---- fused prep: x->bf16 conv | 3x weight pack | edge histogram ----
// pack order: out[((c*4+n)*64+l)*8+j] = Wcat[col=n*32+(l&31)][k=c*16+(l>>5)*8+j]
__device__ __forceinline__ void pack_one(const float* __restrict__ Wl,
                                         const float* __restrict__ Wr,
                                         bool two, int o, u16* __restrict__ out) {
    int j = o & 7;
    int l = (o >> 3) & 63;
    int cn = o >> 9;
    int n = cn & 3;
    int c = cn >> 2;
    int colj = n * 32 + (l & 31);
    int k = c * 16 + (l >> 5) * 8 + j;
    float v;
    if (two) v = (k < DD) ? Wl[colj * DD + k] : Wr[colj * DD + (k - DD)];
    else     v = Wl[colj * DD + k];
    out[o] = f2bf(v);
}

__global__ __launch_bounds__(256) void prep_kernel(
        const float4* __restrict__ x4, ushort4* __restrict__ hb0,
        const float* __restrict__ Wl, const float* __restrict__ Wr,
        const float* __restrict__ W,
        u16* __restrict__ Bpk0, u16* __restrict__ Bpk1, u16* __restrict__ Bpkf,
        const int* __restrict__ ei, int* __restrict__ bcnt) {
    int bid = blockIdx.x;
    int tid = threadIdx.x;
    if (bid < CONVB) {
        int i = bid * 256 + tid;
        float4 v = x4[i];
        ushort4 o;
        o.x = f2bf(v.x); o.y = f2bf(v.y); o.z = f2bf(v.z); o.w = f2bf(v.w);
        hb0[i] = o;
    } else if (bid < CONVB + 128) {
        pack_one(Wl, Wr, true, (bid - CONVB) * 256 + tid, Bpk0);
    } else if (bid < CONVB + 256) {
        pack_one(Wl + DD * DD, Wr + DD * DD, true, (bid - CONVB - 128) * 256 + tid, Bpk1);
    } else if (bid < CONVB + 320) {
        pack_one(W, W, false, (bid - CONVB - 256) * 256 + tid, Bpkf);
    } else {
        // coarse bucket histogram (bcnt zeroed by zero_kernel)
        __shared__ int h[NBUCK];
        for (int i = tid; i < NBUCK; i += 256) h[i] = 0;
        __syncthreads();
        int e0 = (bid - (CONVB + 320)) * EPB;
#pragma unroll
        for (int i = 0; i < 8; i++) {
            int e = e0 + i * 256 + tid;
            if (e < NE) atomicAdd(&h[ei[NE + e] >> 8], 1);
        }
        __syncthreads();
        for (int i = tid; i < NBUCK; i += 256)
            if (h[i]) atomicAdd(&bcnt[i], h[i]);
    }
}

// ---- partition edges into bucket-contiguous packed array ----
__global__ __launch_bounds__(256) void bucket_partition(const int* __restrict__ ei,
                                                        const int* __restrict__ bcnt,
                                                        int* __restrict__ claim,
                                                        unsigned* __restrict__ packed,
                                                        int* __restrict__ rowptr) {
    __shared__ int sc[256];
    __shared__ int bb[NBUCK];
    __shared__ int h[NBUCK];
    __shared__ int base[NBUCK];
    int t = threadIdx.x;
    int v = (t < NBUCK) ? bcnt[t] : 0;
    sc[t] = v;
    __syncthreads();
    for (int o = 1; o < 256; o <<= 1) {
        int u = (t >= o) ? sc[t - o] : 0;
        __syncthreads();
        sc[t] += u;
        __syncthreads();
    }
    if (t < NBUCK) bb[t] = sc[t] - v;
    if (t == 0 && blockIdx.x == 0) rowptr[NN] = NE;
    for (int i = t; i < NBUCK; i += 256) h[i] = 0;
    __syncthreads();
    int e0 = blockIdx.x * EPB;
    int dsts[8], srcs[8];
#pragma unroll
    for (int i = 0; i < 8; i++) {
        int e = e0 + i * 256 + t;
        if (e < NE) {
            dsts[i] = ei[NE + e];
            srcs[i] = ei[e];
            atomicAdd(&h[dsts[i] >> 8], 1);
        } else dsts[i] = -1;
    }
    __syncthreads();
    for (int i = t; i < NBUCK; i += 256) {
        int c = h[i];
        base[i] = c ? bb[i] + atomicAdd(&claim[i], c) : 0;
    }
    __syncthreads();
    for (int i = t; i < NBUCK; i += 256) h[i] = 0;  // reuse as local cursor
    __syncthreads();
#pragma unroll
    for (int i = 0; i < 8; i++) {
        if (dsts[i] >= 0) {
            int bk = dsts[i] >> 8;
            int r = atomicAdd(&h[bk], 1);
            packed[base[bk] + r] = (unsigned)srcs[i] | ((unsigned)(dsts[i] & 255) << 16);
        }
    }
}

// ---- per-bucket counting sort -> rowptr + col ----
__global__ __launch_bounds__(256) void bucket_csr(const unsigned* __restrict__ packed,
                                                  const int* __restrict__ bcnt,
                                                  int* __restrict__ rowptr,
                                                  int* __restrict__ col) {
    __shared__ int sc[256];
    __shared__ int deg[256];
    __shared__ int off[256];
    int t = threadIdx.x;
    int v0 = (t < NBUCK) ? bcnt[t] : 0;
    sc[t] = v0;
    __syncthreads();
    for (int o = 1; o < 256; o <<= 1) {
        int u = (t >= o) ? sc[t - o] : 0;
        __syncthreads();
        sc[t] += u;
        __syncthreads();
    }
    int bk = blockIdx.x;
    int cnt = bcnt[bk];
    int base = sc[bk] - cnt;  // exclusive scan value for this bucket
    deg[t] = 0;
    __syncthreads();
    for (int i = t; i < cnt; i += 256) atomicAdd(&deg[packed[base + i] >> 16], 1);
    __syncthreads();
    int v = deg[t];
    off[t] = v;
    __syncthreads();
    for (int o = 1; o < 256; o <<= 1) {
        int u = (t >= o) ? off[t - o] : 0;
        __syncthreads();
        off[t] += u;
        __syncthreads();
    }
    int ex = off[t] - v;
    int node = (bk << 8) + t;
    if (node < NN) rowptr[node] = base + ex;
    deg[t] = ex;  // reuse as cursor
    __syncthreads();
    for (int i = t; i < cnt; i += 256) {
        unsigned p = packed[base + i];
        int dl = p >> 16;
        int r = atomicAdd(&deg[dl], 1);
        col[base + r] = (int)(p & 0xFFFFu);
    }
}

// ---- segmented max on bf16 (CSR), 16 lanes/node, 16B/lane, unroll-8 ----
__device__ __forceinline__ void vmax8(float* m, uint4 v) {
    m[0] = fmaxf(m[0], bflo(v.x)); m[1] = fmaxf(m[1], bfhi(v.x));
    m[2] = fmaxf(m[2], bflo(v.y)); m[3] = fmaxf(m[3], bfhi(v.y));
    m[4] = fmaxf(m[4], bflo(v.z)); m[5] = fmaxf(m[5], bfhi(v.z));
    m[6] = fmaxf(m[6], bflo(v.w)); m[7] = fmaxf(m[7], bfhi(v.w));
}

__global__ __launch_bounds__(256) void agg_kernel_bf(const uint4* __restrict__ xb4,
                                                     const int* __restrict__ row_ptr,
                                                     const int* __restrict__ col,
                                                     uint4* __restrict__ aggb4) {
    int node = blockIdx.x * 16 + (threadIdx.x >> 4);
    if (node >= NN) return;
    int j = threadIdx.x & 15;
    int s0 = row_ptr[node], s1 = row_ptr[node + 1];
    if (s0 == s1) {
        aggb4[(size_t)node * 16 + j] = make_uint4(0, 0, 0, 0);
        return;
    }
    float m0[8], m1[8], m2[8], m3[8];
#pragma unroll
    for (int q = 0; q < 8; q++) { m0[q] = m1[q] = m2[q] = m3[q] = -INFINITY; }
    int i = s0;
    for (; i + 8 <= s1; i += 8) {
        int c0 = col[i],     c1 = col[i + 1], c2 = col[i + 2], c3 = col[i + 3];
        int c4 = col[i + 4], c5 = col[i + 5], c6 = col[i + 6], c7 = col[i + 7];
        uint4 v0 = xb4[(size_t)c0 * 16 + j];
        uint4 v1 = xb4[(size_t)c1 * 16 + j];
        uint4 v2 = xb4[(size_t)c2 * 16 + j];
        uint4 v3 = xb4[(size_t)c3 * 16 + j];
        uint4 v4 = xb4[(size_t)c4 * 16 + j];
        uint4 v5 = xb4[(size_t)c5 * 16 + j];
        uint4 v6 = xb4[(size_t)c6 * 16 + j];
        uint4 v7 = xb4[(size_t)c7 * 16 + j];
        vmax8(m0, v0); vmax8(m1, v1); vmax8(m2, v2); vmax8(m3, v3);
        vmax8(m0, v4); vmax8(m1, v5); vmax8(m2, v6); vmax8(m3, v7);
    }
    for (; i + 4 <= s1; i += 4) {
        int c0 = col[i], c1 = col[i + 1], c2 = col[i + 2], c3 = col[i + 3];
        uint4 v0 = xb4[(size_t)c0 * 16 + j];
        uint4 v1 = xb4[(size_t)c1 * 16 + j];
        uint4 v2 = xb4[(size_t)c2 * 16 + j];
        uint4 v3 = xb4[(size_t)c3 * 16 + j];
        vmax8(m0, v0); vmax8(m1, v1); vmax8(m2, v2); vmax8(m3, v3);
    }
    for (; i < s1; i++) {
        uint4 v = xb4[(size_t)col[i] * 16 + j];
        vmax8(m0, v);
    }
#pragma unroll
    for (int q = 0; q < 8; q++) m0[q] = fmaxf(fmaxf(m0[q], m1[q]), fmaxf(m2[q], m3[q]));
    uint4 o;  // values are exact bf16 -> pack by truncation
    o.x = (__float_as_uint(m0[0]) >> 16) | (__float_as_uint(m0[1]) & 0xFFFF0000u);
    o.y = (__float_as_uint(m0[2]) >> 16) | (__float_as_uint(m0[3]) & 0xFFFF0000u);
    o.z = (__float_as_uint(m0[4]) >> 16) | (__float_as_uint(m0[5]) & 0xFFFF0000u);
    o.w = (__float_as_uint(m0[6]) >> 16) | (__float_as_uint(m0[7]) & 0xFFFF0000u);
    aggb4[(size_t)node * 16 + j] = o;
}

// ---------------- MFMA GEMM (no LDS: B-fragments straight from L2) ----------------
// out[row][col] = bias[col] + sum_k A[row][k] * Wcat[col][k]
// A = [srcA | srcB] (K=256). 128 rows x 128 cols / block. Layer-0 variant.
__global__ __launch_bounds__(256) void mfma_gemm0(const u16* __restrict__ srcA,
                                                  const u16* __restrict__ srcB,
                                                  const u16* __restrict__ Bpk,
                                                  const float* __restrict__ bias,
                                                  u16* __restrict__ outh) {
    int tid = threadIdx.x;
    int wt = tid >> 6;
    int lane = tid & 63;
    int row0 = blockIdx.x * 128 + wt * 32;
    int rload = row0 + (lane & 31);
    if (rload > NN - 1) rload = NN - 1;  // clamp OOB loads
    int koff = (lane >> 5) * 8;
    const s8v* Bv = (const s8v*)Bpk;

    f16v acc[4];
#pragma unroll
    for (int n = 0; n < 4; n++) acc[n] = (f16v)(0.0f);

#pragma unroll
    for (int c = 0; c < 16; c++) {
        const u16* s = srcA;
        int kk = c * 16;
        if (c >= 8) { s = srcB; kk = (c - 8) * 16; }
        s8v a = *(const s8v*)(s + (size_t)rload * DD + kk + koff);
#pragma unroll
        for (int n = 0; n < 4; n++) {
            s8v b = Bv[(c * 4 + n) * 64 + lane];
            acc[n] = __builtin_amdgcn_mfma_f32_32x32x16_bf16(a, b, acc[n], 0, 0, 0);
        }
    }

    // epilogue: C/D layout col=lane&31, row=(reg&3)+8*(reg>>2)+4*(lane>>5)
    int rowadd = 4 * (lane >> 5);
#pragma unroll
    for (int n = 0; n < 4; n++) {
        int colj = n * 32 + (lane & 31);
        float bj = bias[colj];
#pragma unroll
        for (int r = 0; r < 16; r++) {
            int row = row0 + (r & 3) + 8 * (r >> 2) + rowadd;
            if (row < NN)
                outh[(size_t)row * DD + colj] = f2bf(fmaxf(acc[n][r] + bj, 0.0f));
        }
    }
}

// ---- layer-1 GEMM + final linear fused: relu bf16 tile -> LDS -> 2nd MFMA ----
__global__ __launch_bounds__(256) void gemm_final(const u16* __restrict__ srcA,
                                                  const u16* __restrict__ srcB,
                                                  const u16* __restrict__ Bpk,
                                                  const float* __restrict__ bias,
                                                  const u16* __restrict__ Bpkf,
                                                  const float* __restrict__ bfin,
                                                  float* __restrict__ out) {
    __shared__ u16 As[128 * 128];  // 32 KB, XOR-swizzled rows
    char* Ab = (char*)As;
    int tid = threadIdx.x;
    int wt = tid >> 6;
    int lane = tid & 63;
    int row0 = blockIdx.x * 128;
    int arl = wt * 32 + (lane & 31);
    int rg = row0 + arl;
    if (rg > NN - 1) rg = NN - 1;
    int koff = (lane >> 5) * 8;
    int swz = (arl & 7) << 4;
    const s8v* Bv = (const s8v*)Bpk;

    f16v acc[4];
#pragma unroll
    for (int n = 0; n < 4; n++) acc[n] = (f16v)(0.0f);

#pragma unroll
    for (int c = 0; c < 16; c++) {
        const u16* s = srcA;
        int kk = c * 16;
        if (c >= 8) { s = srcB; kk = (c - 8) * 16; }
        s8v a = *(const s8v*)(s + (size_t)rg * DD + kk + koff);
#pragma unroll
        for (int n = 0; n < 4; n++) {
            s8v b = Bv[(c * 4 + n) * 64 + lane];
            acc[n] = __builtin_amdgcn_mfma_f32_32x32x16_bf16(a, b, acc[n], 0, 0, 0);
        }
    }

    // relu'd bf16 acc -> LDS (this tile IS the A-operand of the final linear)
    int rowadd = 4 * (lane >> 5);
#pragma unroll
    for (int n = 0; n < 4; n++) {
        int colj = n * 32 + (lane & 31);
        float bj = bias[colj];
#pragma unroll
        for (int r = 0; r < 16; r++) {
            int rloc = wt * 32 + (r & 3) + 8 * (r >> 2) + rowadd;
            float v = fmaxf(acc[n][r] + bj, 0.0f);
            *(u16*)(Ab + rloc * 256 + ((colj * 2) ^ ((rloc & 7) << 4))) = f2bf(v);
        }
    }
    __syncthreads();

    // final GEMM: K=128 from LDS, B = Bpkf
    const s8v* Bvf = (const s8v*)Bpkf;
    f16v acc2[4];
#pragma unroll
    for (int n = 0; n < 4; n++) acc2[n] = (f16v)(0.0f);
#pragma unroll
    for (int c = 0; c < 8; c++) {
        s8v a = *(const s8v*)(Ab + arl * 256 + (((c * 16 + koff) * 2) ^ swz));
#pragma unroll
        for (int n = 0; n < 4; n++) {
            s8v b = Bvf[(c * 4 + n) * 64 + lane];
            acc2[n] = __builtin_amdgcn_mfma_f32_32x32x16_bf16(a, b, acc2[n], 0, 0, 0);
        }
    }
#pragma unroll
    for (int n = 0; n < 4; n++) {
        int colj = n * 32 + (lane & 31);
        float bj = bfin[colj];
#pragma unroll
        for (int r = 0; r < 16; r++) {
            int row = row0 + wt * 32 + (r & 3) + 8 * (r >> 2) + rowadd;
            if (row < NN)
                out[(size_t)row * DD + colj] = acc2[n][r] + bj;
        }
    }
}

extern "C" void kernel_launch(void* const* d_in, const int* in_sizes, int n_in,
                              void* d_out, int out_size, void* d_ws, size_t ws_size,
                              hipStream_t stream) {
    const float* x  = (const float*)d_in[0];
    const int*   ei = (const int*)d_in[1];
    const float* Wl = (const float*)d_in[2];
    const float* bl = (const float*)d_in[3];
    const float* Wr = (const float*)d_in[4];
    const float* W  = (const float*)d_in[5];
    const float* b  = (const float*)d_in[6];
    float* out = (float*)d_out;

    // ws layout (16B-aligned chunks)
    u16* aggb = (u16*)d_ws;                         // NN*DD bf16
    u16* hb0  = aggb + (size_t)NN * DD;             // NN*DD
    u16* hb1  = hb0 + (size_t)NN * DD;              // NN*DD
    u16* Bpk0 = hb1 + (size_t)NN * DD;              // 32768
    u16* Bpk1 = Bpk0 + 32768;                       // 32768
    u16* Bpkf = Bpk1 + 32768;                       // 16384
    unsigned* packed = (unsigned*)(Bpkf + 16384);   // NE u32
    int* col    = (int*)(packed + NE);              // NE
    int* rowptr = col + NE;                         // NN+1
    int* bcnt   = rowptr + NN + 1;                  // NBUCK
    int* claim  = bcnt + NBUCK;                     // NBUCK

    dim3 blk(256);
    int gemmBlocks = (NN + 127) / 128;   // 391
    int aggBlocks  = (NN + 15) / 16;     // 3125
    int prepBlocks = CONVB + 320 + PB;   // conv + 3 packs + hist

    // zero bcnt+claim, then fused prep (conv | packs | hist)
    zero_kernel<<<2, blk, 0, stream>>>(bcnt, 2 * NBUCK);
    prep_kernel<<<prepBlocks, blk, 0, stream>>>(
        (const float4*)x, (ushort4*)hb0, Wl, Wr, W, Bpk0, Bpk1, Bpkf, ei, bcnt);

    // CSR build
    bucket_partition<<<PB, blk, 0, stream>>>(ei, bcnt, claim, packed, rowptr);
    bucket_csr<<<NBUCK, blk, 0, stream>>>(packed, bcnt, rowptr, col);

    // Layer 0
    agg_kernel_bf<<<aggBlocks, blk, 0, stream>>>((const uint4*)hb0, rowptr, col, (uint4*)aggb);
    mfma_gemm0<<<gemmBlocks, blk, 0, stream>>>(aggb, hb0, Bpk0, bl, hb1);

    // Layer 1 + final linear fused
    agg_kernel_bf<<<aggBlocks, blk, 0, stream>>>((const uint4*)hb1, rowptr, col, (uint4*)aggb);
    gemm_final<<<gemmBlocks, blk, 0, stream>>>(aggb, hb1, Bpk1, bl + DD, Bpkf, b, out);
}